// Round 12
// baseline (433.610 us; speedup 1.0000x reference)
//
#include <hip/hip_runtime.h>

#define ALPHA   0.15f
#define RA      (1e-4f * 0.15f)                  // RHO*ALPHA
#define THRESH  ((1.0f + 0.01f) * 1e-4f * 0.15f) // (1+eps)*RHO*ALPHA
#define NITER   20
#define NS      8
#define NMIR    64       // flag mirrors to spread atomicOr contention
#define CHW     16       // rows per wave (4 lanes/row, 2 seeds/lane)
#define BLK     256      // 4 waves/block
#define W4      (BLK / 64)
#define SPAN    384      // LDS cols capacity per wave (mean 256, +8 sigma)
#define NBIN    8        // scatter row-bins (== XCDs)
#define ECHUNK  2048     // edges per scatter chunk

// ---------------------------------------------------------------------------
// init: pd=(0,d0); frontier compaction for iter 0 (seed rows only, analytic
// rank - no atomics); remapA = idx|-1; dincA rows for nonzero seeds; cursor=0;
// flag mirrors; per-iteration compaction counters zeroed; per-block deg sums.
// ---------------------------------------------------------------------------
__global__ void init_kernel(const float* __restrict__ deg, const int* __restrict__ seeds,
                            float2* __restrict__ pd, float* __restrict__ dincA,
                            int* __restrict__ remapA, int* __restrict__ cursor,
                            int* __restrict__ flagM, int* __restrict__ gcnt,
                            int* __restrict__ blockSums, int N) {
    int idx = blockIdx.x * blockDim.x + threadIdx.x;

    // per-block deg sum (for the scan)
    int v = (idx < N) ? (int)deg[idx] : 0;
#pragma unroll
    for (int o = 1; o < 64; o <<= 1) v += __shfl_xor(v, o);
    __shared__ int ws[4];
    if ((threadIdx.x & 63) == 0) ws[threadIdx.x >> 6] = v;
    __syncthreads();
    if (threadIdx.x == 0) blockSums[blockIdx.x] = ws[0] + ws[1] + ws[2] + ws[3];

    if (idx < NITER) gcnt[idx] = 0;
    if (idx < (NITER + 1) * NMIR) {
        int fv = 0;
        if (idx == 0) {
            for (int s = 0; s < NS; ++s) {
                float m = ALPHA / fmaxf(deg[seeds[s]], 1e-12f);
                if (m > THRESH) fv |= (1 << s);
            }
        }
        flagM[idx] = fv;
    }
    if (idx >= N) return;
    cursor[idx] = 0;

    float dv[NS];
    bool  Sv[NS];
    bool nz = false;
#pragma unroll
    for (int s = 0; s < NS; ++s) dv[s] = 0.f;
#pragma unroll
    for (int s = 0; s < NS; ++s) {
        if (seeds[s] == idx) dv[s] = -ALPHA / fmaxf(deg[idx], 1e-12f);
    }
    float den = deg[idx] + 1e-12f;
#pragma unroll
    for (int s = 0; s < NS; ++s) {
        pd[idx * NS + s] = make_float2(0.f, dv[s]);
        Sv[s] = (0.f - dv[s]) >= RA;
        if (Sv[s]) nz = true;
    }
    int rmp = -1;
    if (nz) {   // rank among distinct nonzero seed-nodes with smaller node id
        int rank = 0;
        for (int s = 0; s < NS; ++s) {
            int sd = seeds[s];
            bool first = true;
            for (int t = 0; t < s; ++t) if (seeds[t] == sd) first = false;
            if (first && sd < idx) {
                if ((ALPHA / fmaxf(deg[sd], 1e-12f)) >= RA) rank++;
            }
        }
        rmp = rank;
#pragma unroll
        for (int s = 0; s < NS; ++s)
            dincA[(size_t)rank * NS + s] = Sv[s] ? (-(dv[s] + RA) / den) : 0.f;
    }
    remapA[idx] = rmp;
}

// ---------------------------------------------------------------------------
// scan of per-block sums + per-element offsets (two tiny kernels)
// ---------------------------------------------------------------------------
__global__ void scan_sums_kernel(const int* __restrict__ blockSums, int* __restrict__ blockOffs, int nB) {
    __shared__ int buf[1024];
    int t = threadIdx.x;
    int v = (t < nB) ? blockSums[t] : 0;
    buf[t] = v;
    __syncthreads();
    for (int o = 1; o < 1024; o <<= 1) {
        int u = (t >= o) ? buf[t - o] : 0;
        __syncthreads();
        buf[t] += u;
        __syncthreads();
    }
    if (t < nB) blockOffs[t] = buf[t] - v;  // exclusive
}

__global__ void write_offs_kernel(const float* __restrict__ deg, const int* __restrict__ blockOffs,
                                  int* __restrict__ offs, int N, int E) {
    int t = threadIdx.x;
    int i = blockIdx.x * 256 + t;
    int v = (i < N) ? (int)deg[i] : 0;
    __shared__ int buf[256];
    buf[t] = v;
    __syncthreads();
    for (int o = 1; o < 256; o <<= 1) {
        int u = (t >= o) ? buf[t - o] : 0;
        __syncthreads();
        buf[t] += u;
        __syncthreads();
    }
    int excl = buf[t] - v;
    if (i < N) offs[i] = blockOffs[blockIdx.x] + excl;
    if (i == 0) offs[N] = E;   // sum(deg) == E by construction (deg = bincount(row))
}

// ---------------------------------------------------------------------------
// scatter COO -> CSR, XCD-binned; record = plain col (4B).
// ---------------------------------------------------------------------------
__global__ void scatter_kernel(const int* __restrict__ row, const int* __restrict__ col,
                               const int* __restrict__ offs, int* __restrict__ cursor,
                               int* __restrict__ cols, int E, int N) {
    int bin = blockIdx.x & (NBIN - 1);
    int chunk = blockIdx.x >> 3;
    int binW = (N + NBIN - 1) / NBIN;
    int binLo = bin * binW;
    int binHi = min(N, binLo + binW);
    int e = chunk * ECHUNK + threadIdx.x;
#pragma unroll
    for (int i = 0; i < ECHUNK / 256; ++i, e += 256) {
        if (e < E) {
            int r = row[e];
            if (r >= binLo && r < binHi) {
                int pos = offs[r] + atomicAdd(&cursor[r], 1);
                cols[pos] = col[e];
            }
        }
    }
}

// ---------------------------------------------------------------------------
// one iteration. Wave = 16 rows x 4 lanes/row (lane quarter q owns seeds
// 2q,2q+1). Staging: sCols[i] = remapIn[cols[i]] (compact idx or -1) -> no
// bitmask broadcast. Gather: float2 per frontier edge from the DENSE dinc
// buffer (|F|*32B, L2-resident). Fused scalar update; output compaction via
// per-wave ballot + one atomicAdd of popcount; pd store skipped when dead.
// No cross-wave state -> no barriers; 8 blocks/CU.
// ---------------------------------------------------------------------------
__global__ __launch_bounds__(BLK, 8) void update_kernel(
        const int* __restrict__ offs, const int* __restrict__ cols,
        const float* __restrict__ deg,
        const int* __restrict__ flagIn, int* __restrict__ flagOut,
        const int* __restrict__ remapIn, int* __restrict__ remapOut,
        const float* __restrict__ dincIn, float* __restrict__ dincOut,
        int* __restrict__ gc,
        float2* __restrict__ pd, float* __restrict__ outp, int last, int N) {
    __shared__ int sColsAll[W4 * SPAN];
    int tid = threadIdx.x;
    int w = tid >> 6;
    int lane = tid & 63;
    int wid = blockIdx.x * W4 + w;
    int base = wid * CHW;
    int* sCols = sColsAll + w * SPAN;

    int r4 = lane >> 2;                     // row-in-wave 0..15
    int q  = lane & 3;                      // quarter: seeds 2q, 2q+1
    int row = base + r4;
    bool rok = row < N;

    // iteration-k flags: OR over 64 mirrors via shuffles (grid-uniform value)
    int fm = flagIn[lane];
#pragma unroll
    for (int o = 1; o < 64; o <<= 1) fm |= __shfl_xor(fm, o);

    if (fm == 0) {                          // globally converged: p frozen
        if (last && rok) {
            float4 pv4 = ((const float4*)(pd + (size_t)row * NS))[q];
            outp[(2 * q + 0) * (size_t)N + row] = pv4.x;
            outp[(2 * q + 1) * (size_t)N + row] = pv4.z;
        }
        return;
    }

    int offv = 0;
    if (lane <= CHW) offv = offs[min(base + lane, N)];
    int off0 = __shfl(offv, 0);
    int span = __shfl(offv, CHW) - off0;
    int e0 = __shfl(offv, r4);
    int e1 = __shfl(offv, r4 + 1);
    int rel = e0 - off0, ndg = e1 - e0;

    bool fits = (span <= SPAN);
    if (fits) {                             // stage compact indices (or -1)
        for (int i = lane; i < span; i += 64) {
            int cc = cols[off0 + i];
            sCols[i] = remapIn[cc];
        }
    }
    // no barrier needed: sCols region is wave-private

    int mx = ndg;
#pragma unroll
    for (int o = 1; o < 64; o <<= 1) mx = max(mx, __shfl_xor(mx, o));

    // hoisted row state (issues before/with the gather loop)
    float dg = 1.0f;
    float4 pdv = make_float4(0.f, 0.f, 0.f, 0.f);
    if (rok) {
        dg = deg[row];
        pdv = ((const float4*)(pd + (size_t)row * NS))[q];
    }

    float a0 = 0.f, a1 = 0.f;
    const float2* din2 = (const float2*)dincIn;
    if (fits) {
#pragma unroll 8
        for (int i = 0; i < mx; ++i) {
            int cc = (i < ndg) ? sCols[rel + i] : -1;
            if (cc >= 0) {
                float2 v = din2[(size_t)cc * 4 + q];
                a0 += v.x; a1 += v.y;
            }
        }
    } else {                                // astronomically rare slice
        for (int i = 0; i < mx; ++i) {
            if (i < ndg) {
                int cc = remapIn[cols[e0 + i]];
                if (cc >= 0) {
                    float2 v = din2[(size_t)cc * 4 + q];
                    a0 += v.x; a1 += v.y;
                }
            }
        }
    }

    float di = 1.0f / fmaxf(dg, 1e-12f);
    float hf = 0.5f * (1.0f - ALPHA) * di;
    float den = dg + 1e-12f;

    float p0 = pdv.x, d0 = pdv.y, p1 = pdv.z, d1 = pdv.w;
    float w0, w1;
    unsigned fireN = 0, nzN = 0;
    bool chg = false;

#define UPD(PK, DK, AK, B, WK) { \
        bool S = (PK - DK) >= RA; \
        float dpkv = S ? -(DK + RA) : 0.f; \
        float dS  = (1.0f - di) * DK - RA * di - hf * dpkv - hf * AK; \
        float dnb = DK - hf * AK; \
        bool aa = (fm >> (2 * q + B)) & 1; \
        float nd2 = aa ? (S ? dS : dnb) : DK; \
        float np2 = aa ? (S ? PK + dpkv : PK) : PK; \
        bool S2 = (np2 - nd2) >= RA; \
        WK = S2 ? (-(nd2 + RA) / den) : 0.f; \
        if (aa && (S || AK != 0.f)) chg = true; \
        if (aa && fabsf(nd2) > THRESH) fireN |= 1u << B; \
        if (WK != 0.f) nzN |= 1u << B; \
        PK = np2; DK = nd2; }
    UPD(p0, d0, a0, 0, w0)
    UPD(p1, d1, a1, 1, w1)
#undef UPD

    if (last) {
        if (rok) {
            outp[(2 * q + 0) * (size_t)N + row] = p0;
            outp[(2 * q + 1) * (size_t)N + row] = p1;
        }
    } else {
        int nzl = (nzN != 0) ? 1 : 0;
        nzl |= __shfl_xor(nzl, 1);
        nzl |= __shfl_xor(nzl, 2);                  // row-any-nonzero (all 4 lanes)

        // frontier compaction: one atomicAdd(popcount) per wave
        unsigned long long bal = __ballot(q == 0 && rok && nzl);
        int cnt = __popcll(bal);
        int bidx = 0;
        if (lane == 0 && cnt) bidx = atomicAdd(gc, cnt);
        bidx = __shfl(bidx, 0);
        int rank = __popcll(bal & ((1ull << (4 * r4)) - 1));

        if (rok) {
            int cidx = bidx + rank;
            if (q == 0) remapOut[row] = nzl ? cidx : -1;
            if (nzl) ((float2*)dincOut)[(size_t)cidx * 4 + q] = make_float2(w0, w1);
            if (chg) ((float4*)(pd + (size_t)row * NS))[q] = make_float4(p0, d0, p1, d1);
        }

        int wm = 0;
        unsigned long long bb0 = __ballot(fireN & 1);
        unsigned long long bb1 = __ballot((fireN >> 1) & 1);
#pragma unroll
        for (int qq = 0; qq < 4; ++qq) {
            if (bb0 & (0x1111111111111111ull << qq)) wm |= 1 << (2 * qq);
            if (bb1 & (0x1111111111111111ull << qq)) wm |= 1 << (2 * qq + 1);
        }
        if (wm && lane == 0) {
            int hsh = wid & (NMIR - 1);
            int cur = __hip_atomic_load(&flagOut[hsh], __ATOMIC_RELAXED,
                                        __HIP_MEMORY_SCOPE_AGENT);
            if ((cur & wm) != wm) atomicOr(&flagOut[hsh], wm);
        }
    }
}

extern "C" void kernel_launch(void* const* d_in, const int* in_sizes, int n_in,
                              void* d_out, int out_size, void* d_ws, size_t ws_size,
                              hipStream_t stream) {
    const int*   adj_row = (const int*)  d_in[0];
    const int*   adj_col = (const int*)  d_in[1];
    const float* deg     = (const float*)d_in[3];
    const int*   seeds   = (const int*)  d_in[4];
    const int E = in_sizes[0];
    const int N = in_sizes[3];
    float* out = (float*)d_out;

    // workspace carve-up (256B aligned). dincA aliases d_out: din at k=19 is
    // dincB (odd k reads B), and at k=19 we only write outp (no compaction),
    // so overwriting the dincA region with the final output is safe.
    char* base = (char*)d_ws;
    size_t off = 0;
    auto carve = [&](size_t bytes) -> void* {
        off = (off + 255) & ~(size_t)255;
        void* ptr = base + off;
        off += bytes;
        return ptr;
    };
    float2* pd     = (float2*)carve((size_t)N * NS * 8);
    float*  dincB  = (float*) carve((size_t)N * NS * 4);
    int*    cols   = (int*)   carve((size_t)(E + SPAN) * 4);
    int*    offs   = (int*)   carve((size_t)(N + 1) * 4);
    int*    cursor = (int*)   carve((size_t)N * 4);
    int*    bsums  = (int*)   carve((size_t)1024 * 4);
    int*    boffs  = (int*)   carve((size_t)1024 * 4);
    int*    flagM  = (int*)   carve((size_t)(NITER + 1) * NMIR * 4);
    int*    remapA = (int*)   carve((size_t)N * 4);
    int*    remapB = (int*)   carve((size_t)N * 4);
    int*    gcnt   = (int*)   carve((size_t)NITER * 4);
    float*  dincA  = out;     // aliased

    int nb = (N + 255) / 256;      // 391 blocks
    init_kernel<<<nb, 256, 0, stream>>>(deg, seeds, pd, dincA, remapA, cursor,
                                        flagM, gcnt, bsums, N);
    scan_sums_kernel<<<1, 1024, 0, stream>>>(bsums, boffs, nb);
    write_offs_kernel<<<nb, 256, 0, stream>>>(deg, boffs, offs, N, E);
    int chunks = (E + ECHUNK - 1) / ECHUNK;
    scatter_kernel<<<chunks * NBIN, 256, 0, stream>>>(adj_row, adj_col, offs, cursor,
                                                      cols, E, N);

    float* din   = dincA;
    float* dout_ = dincB;
    int*   rIn   = remapA;
    int*   rOut  = remapB;
    int rowsPerBlk = W4 * CHW;                         // 64
    int ub = (N + rowsPerBlk - 1) / rowsPerBlk;        // 1563 blocks
    for (int k = 0; k < NITER; ++k) {
        int last = (k == NITER - 1) ? 1 : 0;
        update_kernel<<<ub, BLK, 0, stream>>>(offs, cols, deg,
                                              flagM + k * NMIR, flagM + (k + 1) * NMIR,
                                              rIn, rOut, din, dout_, gcnt + k,
                                              pd, out, last, N);
        float* t = din; din = dout_; dout_ = t;
        int* rt = rIn; rIn = rOut; rOut = rt;
    }
}